// Round 1
// baseline (1874.930 us; speedup 1.0000x reference)
//
#include <hip/hip_runtime.h>
#include <math.h>

// Problem constants
#define BB 8
#define TT 1024
#define CC 1024
#define HH 16
#define HKV 4
#define HD 64
#define GG 4
#define MM (BB*TT)   // 8192

typedef __attribute__((ext_vector_type(8))) short bf16x8;
typedef __attribute__((ext_vector_type(4))) float f32x4;

__device__ __forceinline__ float b2f(unsigned short x){
    union{unsigned int i; float f;} u; u.i = ((unsigned int)x)<<16; return u.f;
}
__device__ __forceinline__ float b2f_lo(unsigned int w){
    union{unsigned int i; float f;} u; u.i = w<<16; return u.f;
}
__device__ __forceinline__ float b2f_hi(unsigned int w){
    union{unsigned int i; float f;} u; u.i = w & 0xffff0000u; return u.f;
}
__device__ __forceinline__ unsigned short f2b(float f){
    union{float f; unsigned int i;} u; u.f = f;
    unsigned int r = u.i + 0x7fffu + ((u.i>>16)&1u);
    return (unsigned short)(r>>16);
}

// ---------------- fp32 -> bf16 conversion (vectorized grid-stride) ----------
__global__ __launch_bounds__(256) void cvt_f32_bf16(const float* __restrict__ in,
                                                    unsigned short* __restrict__ out,
                                                    int n4){
    int i = blockIdx.x*256 + threadIdx.x;
    if (i < n4){
        float4 f = ((const float4*)in)[i];
        ushort4 o;
        o.x = f2b(f.x); o.y = f2b(f.y); o.z = f2b(f.z); o.w = f2b(f.w);
        ((ushort4*)out)[i] = o;
    }
}

// ---------------- bf16 MFMA GEMM: C(MxN fp32) = A(MxK) * Bt(NxK)^T ----------
// m93-style: block 256 = 4 waves, tile 128x128, BK=32, wave does 64x64.
__global__ __launch_bounds__(256) void gemm_bt(const unsigned short* __restrict__ A,
                                               const unsigned short* __restrict__ Bt,
                                               float* __restrict__ Cc,
                                               int M, int N, int K){
    __shared__ __align__(16) unsigned short As[128*32];
    __shared__ __align__(16) unsigned short Bs[128*32];
    const int tid  = threadIdx.x;
    const int wid  = tid >> 6;
    const int lane = tid & 63;
    const int wm   = wid >> 1;       // 0..1
    const int wn   = wid & 1;        // 0..1
    const int l16  = lane & 15;
    const int quad = lane >> 4;
    const int bm = blockIdx.y * 128;
    const int bn = blockIdx.x * 128;

    f32x4 acc[4][4] = {};

    for (int k0 = 0; k0 < K; k0 += 32){
        __syncthreads();
        #pragma unroll
        for (int it = 0; it < 2; ++it){
            int idx = it*256 + tid;          // 0..511, chunk = 8 bf16 = 16B
            int row = idx >> 2;
            int cc  = idx & 3;
            ((uint4*)As)[idx] = *(const uint4*)(A  + (size_t)(bm+row)*K + k0 + cc*8);
            ((uint4*)Bs)[idx] = *(const uint4*)(Bt + (size_t)(bn+row)*K + k0 + cc*8);
        }
        __syncthreads();

        bf16x8 af[4], bfr[4];
        #pragma unroll
        for (int i = 0; i < 4; ++i)
            af[i] = *(const bf16x8*)(As + (wm*64 + i*16 + l16)*32 + quad*8);
        #pragma unroll
        for (int j = 0; j < 4; ++j)
            bfr[j] = *(const bf16x8*)(Bs + (wn*64 + j*16 + l16)*32 + quad*8);

        #pragma unroll
        for (int i = 0; i < 4; ++i)
            #pragma unroll
            for (int j = 0; j < 4; ++j)
                acc[i][j] = __builtin_amdgcn_mfma_f32_16x16x32_bf16(af[i], bfr[j], acc[i][j], 0, 0, 0);
    }

    // C/D layout: col = lane&15, row = quad*4 + reg
    #pragma unroll
    for (int i = 0; i < 4; ++i){
        int row0 = wm*64 + i*16 + quad*4;
        #pragma unroll
        for (int j = 0; j < 4; ++j){
            int col = bn + wn*64 + j*16 + l16;
            #pragma unroll
            for (int r = 0; r < 4; ++r){
                Cc[(size_t)(bm + row0 + r)*N + col] = acc[i][j][r];
            }
        }
    }
}

// ---------------- RMSNorm + RoPE + relayout ---------------------------------
// One wave per (row, unit): units 0..15 -> q head, 16..19 -> k head, 20..23 -> v head
__global__ __launch_bounds__(256) void norm_rope(const float* __restrict__ Qf,
                                                 const float* __restrict__ KVf,
                                                 const float* __restrict__ qw,
                                                 const float* __restrict__ kw,
                                                 unsigned short* __restrict__ qa,
                                                 unsigned short* __restrict__ ka,
                                                 unsigned short* __restrict__ va){
    int wid  = blockIdx.x*4 + (threadIdx.x >> 6);
    int lane = threadIdx.x & 63;
    int row  = wid / 24;
    int u    = wid - row*24;
    int b = row >> 10;
    int t = row & 1023;

    if (u >= 20){
        // V: plain convert + relayout
        int n = u - 20;
        float val = KVf[(size_t)row*512 + 256 + n*64 + lane];
        va[(((size_t)(b*HKV + n))*TT + t)*HD + lane] = f2b(val);
        return;
    }

    float val;
    const float* w;
    if (u < 16){ val = Qf[(size_t)row*CC + u*64 + lane];        w = qw; }
    else       { val = KVf[(size_t)row*512 + (u-16)*64 + lane]; w = kw; }

    // RMS over 64 lanes
    float ss = val*val;
    #pragma unroll
    for (int off = 32; off > 0; off >>= 1) ss += __shfl_xor(ss, off, 64);
    float normed = val * rsqrtf(ss*(1.0f/64.0f) + 1e-6f) * w[lane];

    // RoPE: pairs (d, d+32); freq_i = t * theta^(-i/32)
    int i = lane & 31;
    float freq = (float)t * exp2f(-(float)i * (13.287712379549449f/32.0f));
    float s, c;
    sincosf(freq, &s, &c);
    float other = __shfl_xor(normed, 32, 64);
    float outv = (lane < 32) ? (normed*c + other*s) : (-other*s + normed*c);

    if (u < 16){
        qa[(((size_t)(b*HH + u))*TT + t)*HD + lane] = f2b(outv);
    } else {
        ka[(((size_t)(b*HKV + (u-16)))*TT + t)*HD + lane] = f2b(outv);
    }
}

// ---------------- Attention: one wave per query row -------------------------
__global__ __launch_bounds__(256) void attn(const unsigned short* __restrict__ qa,
                                            const unsigned short* __restrict__ ka,
                                            const unsigned short* __restrict__ va,
                                            unsigned short* __restrict__ ya){
    __shared__ __align__(16) float qs[4][64];
    __shared__ __align__(16) float sc[4][1024];
    const int wave = threadIdx.x >> 6;
    const int lane = threadIdx.x & 63;
    const int tq = blockIdx.x*4 + wave;
    const int h  = blockIdx.y;
    const int b  = blockIdx.z;
    const int n  = h >> 2;   // GQA group

    float qv = b2f(qa[(((size_t)(b*HH + h))*TT + tq)*HD + lane]) * 0.125f;
    qs[wave][lane] = qv;
    __syncthreads();

    const unsigned short* kbase = ka + ((size_t)(b*HKV + n))*TT*HD;
    const unsigned short* vbase = va + ((size_t)(b*HKV + n))*TT*HD;

    // Phase 1: scores (softcapped, masked) -> LDS; track max
    float tmax = -INFINITY;
    for (int j0 = 0; j0 <= tq; j0 += 64){
        int j = j0 + lane;
        const uint4* kr = (const uint4*)(kbase + (size_t)j*HD);
        float s = 0.0f;
        #pragma unroll
        for (int cq = 0; cq < 8; ++cq){
            uint4 kk = kr[cq];
            float4 q1 = *(const float4*)&qs[wave][cq*8];
            float4 q2 = *(const float4*)&qs[wave][cq*8 + 4];
            s += q1.x*b2f_lo(kk.x) + q1.y*b2f_hi(kk.x)
               + q1.z*b2f_lo(kk.y) + q1.w*b2f_hi(kk.y)
               + q2.x*b2f_lo(kk.z) + q2.y*b2f_hi(kk.z)
               + q2.z*b2f_lo(kk.w) + q2.w*b2f_hi(kk.w);
        }
        s = 50.0f * tanhf(s * 0.02f);
        if (j > tq) s = -INFINITY;
        sc[wave][j] = s;
        tmax = fmaxf(tmax, s);
    }
    #pragma unroll
    for (int off = 32; off > 0; off >>= 1) tmax = fmaxf(tmax, __shfl_xor(tmax, off, 64));
    __syncthreads();

    // Phase 2: exp + sum
    float lsum = 0.0f;
    for (int j0 = 0; j0 <= tq; j0 += 64){
        int j = j0 + lane;
        float p = expf(sc[wave][j] - tmax);
        sc[wave][j] = p;
        lsum += p;
    }
    #pragma unroll
    for (int off = 32; off > 0; off >>= 1) lsum += __shfl_xor(lsum, off, 64);
    float inv = 1.0f / lsum;
    __syncthreads();

    // Phase 3: PV, lane = dim
    float acc = 0.0f;
    int j = 0;
    for (; j + 4 <= tq + 1; j += 4){
        float4 p = *(const float4*)&sc[wave][j];
        acc += p.x * b2f(vbase[(size_t)(j+0)*HD + lane]);
        acc += p.y * b2f(vbase[(size_t)(j+1)*HD + lane]);
        acc += p.z * b2f(vbase[(size_t)(j+2)*HD + lane]);
        acc += p.w * b2f(vbase[(size_t)(j+3)*HD + lane]);
    }
    for (; j <= tq; ++j)
        acc += sc[wave][j] * b2f(vbase[(size_t)j*HD + lane]);

    // y layout: (B, T, H, HD)
    ya[(((size_t)(b*TT + tq))*HH + h)*HD + lane] = f2b(acc * inv);
}

// ---------------- launch ----------------------------------------------------
extern "C" void kernel_launch(void* const* d_in, const int* in_sizes, int n_in,
                              void* d_out, int out_size, void* d_ws, size_t ws_size,
                              hipStream_t stream) {
    const float* x    = (const float*)d_in[0];
    const float* w_q  = (const float*)d_in[1];
    const float* w_kv = (const float*)d_in[2];
    const float* w_c  = (const float*)d_in[3];
    const float* qw   = (const float*)d_in[4];
    const float* kw   = (const float*)d_in[5];
    float* out = (float*)d_out;

    char* ws = (char*)d_ws;
    unsigned short* xb   = (unsigned short*)(ws);
    unsigned short* wqb  = (unsigned short*)(ws + ((size_t)16<<20));
    unsigned short* wkvb = (unsigned short*)(ws + ((size_t)18<<20));
    unsigned short* wcb  = (unsigned short*)(ws + ((size_t)19<<20));
    float*          Qf   = (float*)(ws + ((size_t)21<<20));
    float*          KVf  = (float*)(ws + ((size_t)53<<20));
    unsigned short* qa   = (unsigned short*)(ws + ((size_t)69<<20));
    unsigned short* ka   = (unsigned short*)(ws + ((size_t)85<<20));
    unsigned short* va   = (unsigned short*)(ws + ((size_t)89<<20));
    unsigned short* ya   = (unsigned short*)(ws + ((size_t)93<<20));

    // 1) convert inputs to bf16
    cvt_f32_bf16<<<dim3((MM*CC/4)/256), 256, 0, stream>>>(x, xb, MM*CC/4);
    cvt_f32_bf16<<<dim3((CC*CC/4)/256), 256, 0, stream>>>(w_q, wqb, CC*CC/4);
    cvt_f32_bf16<<<dim3((512*CC/4)/256), 256, 0, stream>>>(w_kv, wkvb, 512*CC/4);
    cvt_f32_bf16<<<dim3((CC*CC/4)/256), 256, 0, stream>>>(w_c, wcb, CC*CC/4);

    // 2) Q = x @ w_q^T   (8192 x 1024 x 1024)
    gemm_bt<<<dim3(CC/128, MM/128), 256, 0, stream>>>(xb, wqb, Qf, MM, CC, CC);
    // 3) KV = x @ w_kv^T (8192 x 512 x 1024)
    gemm_bt<<<dim3(512/128, MM/128), 256, 0, stream>>>(xb, wkvb, KVf, MM, 512, CC);

    // 4) RMSNorm + RoPE + relayout
    norm_rope<<<dim3(MM*24/4), 256, 0, stream>>>(Qf, KVf, qw, kw, qa, ka, va);

    // 5) attention
    attn<<<dim3(TT/4, HH, BB), 256, 0, stream>>>(qa, ka, va, ya);

    // 6) out = y @ w_c^T
    gemm_bt<<<dim3(CC/128, MM/128), 256, 0, stream>>>(ya, wcb, out, MM, CC, CC);
}

// Round 2
// 410.911 us; speedup vs baseline: 4.5629x; 4.5629x over previous
//
#include <hip/hip_runtime.h>
#include <math.h>

// Problem constants
#define BB 8
#define TT 1024
#define CC 1024
#define HH 16
#define HKV 4
#define HD 64
#define GG 4
#define MM (BB*TT)   // 8192
#define LOG2E 1.4426950408889634f

typedef __attribute__((ext_vector_type(8))) short bf16x8;
typedef __attribute__((ext_vector_type(4))) float f32x4;

__device__ __forceinline__ float b2f(unsigned short x){
    union{unsigned int i; float f;} u; u.i = ((unsigned int)x)<<16; return u.f;
}
__device__ __forceinline__ unsigned short f2b(float f){
    union{float f; unsigned int i;} u; u.f = f;
    unsigned int r = u.i + 0x7fffu + ((u.i>>16)&1u);
    return (unsigned short)(r>>16);
}

// ---------------- fp32 -> bf16 conversion (vectorized) ----------------------
__global__ __launch_bounds__(256) void cvt_f32_bf16(const float* __restrict__ in,
                                                    unsigned short* __restrict__ out,
                                                    int n4){
    int i = blockIdx.x*256 + threadIdx.x;
    if (i < n4){
        float4 f = ((const float4*)in)[i];
        ushort4 o;
        o.x = f2b(f.x); o.y = f2b(f.y); o.z = f2b(f.z); o.w = f2b(f.w);
        ((ushort4*)out)[i] = o;
    }
}

// ---------------- bf16 MFMA GEMM: C(MxN fp32) = A(MxK) * Bt(NxK)^T ----------
__global__ __launch_bounds__(256) void gemm_bt(const unsigned short* __restrict__ A,
                                               const unsigned short* __restrict__ Bt,
                                               float* __restrict__ Cc,
                                               int M, int N, int K){
    __shared__ __align__(16) unsigned short As[128*32];
    __shared__ __align__(16) unsigned short Bs[128*32];
    const int tid  = threadIdx.x;
    const int wid  = tid >> 6;
    const int lane = tid & 63;
    const int wm   = wid >> 1;
    const int wn   = wid & 1;
    const int l16  = lane & 15;
    const int quad = lane >> 4;
    const int bm = blockIdx.y * 128;
    const int bn = blockIdx.x * 128;

    f32x4 acc[4][4] = {};

    for (int k0 = 0; k0 < K; k0 += 32){
        __syncthreads();
        #pragma unroll
        for (int it = 0; it < 2; ++it){
            int idx = it*256 + tid;
            int row = idx >> 2;
            int cc  = idx & 3;
            ((uint4*)As)[idx] = *(const uint4*)(A  + (size_t)(bm+row)*K + k0 + cc*8);
            ((uint4*)Bs)[idx] = *(const uint4*)(Bt + (size_t)(bn+row)*K + k0 + cc*8);
        }
        __syncthreads();

        bf16x8 af[4], bfr[4];
        #pragma unroll
        for (int i = 0; i < 4; ++i)
            af[i] = *(const bf16x8*)(As + (wm*64 + i*16 + l16)*32 + quad*8);
        #pragma unroll
        for (int j = 0; j < 4; ++j)
            bfr[j] = *(const bf16x8*)(Bs + (wn*64 + j*16 + l16)*32 + quad*8);

        #pragma unroll
        for (int i = 0; i < 4; ++i)
            #pragma unroll
            for (int j = 0; j < 4; ++j)
                acc[i][j] = __builtin_amdgcn_mfma_f32_16x16x32_bf16(af[i], bfr[j], acc[i][j], 0, 0, 0);
    }

    #pragma unroll
    for (int i = 0; i < 4; ++i){
        int row0 = wm*64 + i*16 + quad*4;
        #pragma unroll
        for (int j = 0; j < 4; ++j){
            int col = bn + wn*64 + j*16 + l16;
            #pragma unroll
            for (int r = 0; r < 4; ++r){
                Cc[(size_t)(bm + row0 + r)*N + col] = acc[i][j][r];
            }
        }
    }
}

// ---------------- RMSNorm + RoPE + relayout (Q and K only) ------------------
__global__ __launch_bounds__(256) void norm_rope(const float* __restrict__ Qf,
                                                 const float* __restrict__ KVf,
                                                 const float* __restrict__ qw,
                                                 const float* __restrict__ kw,
                                                 unsigned short* __restrict__ qa,
                                                 unsigned short* __restrict__ ka){
    int wid  = blockIdx.x*4 + (threadIdx.x >> 6);
    int lane = threadIdx.x & 63;
    int row  = wid / 20;
    int u    = wid - row*20;
    int b = row >> 10;
    int t = row & 1023;

    float val;
    const float* w;
    if (u < 16){ val = Qf[(size_t)row*CC + u*64 + lane];        w = qw; }
    else       { val = KVf[(size_t)row*512 + (u-16)*64 + lane]; w = kw; }

    float ss = val*val;
    #pragma unroll
    for (int off = 32; off > 0; off >>= 1) ss += __shfl_xor(ss, off, 64);
    float normed = val * rsqrtf(ss*(1.0f/64.0f) + 1e-6f) * w[lane];

    int i = lane & 31;
    float freq = (float)t * exp2f(-(float)i * (13.287712379549449f/32.0f));
    float s, c;
    sincosf(freq, &s, &c);
    float other = __shfl_xor(normed, 32, 64);
    float outv = (lane < 32) ? (normed*c + other*s) : (-other*s + normed*c);

    if (u < 16){
        qa[(((size_t)(b*HH + u))*TT + t)*HD + lane] = f2b(outv);
    } else {
        ka[(((size_t)(b*HKV + (u-16)))*TT + t)*HD + lane] = f2b(outv);
    }
}

// ---------------- V transpose: KVf fp32 (b,t,[256+n*64+d]) -> vat bf16 (b,n,d,t)
__global__ __launch_bounds__(256) void vtrans(const float* __restrict__ KVf,
                                              unsigned short* __restrict__ vat){
    __shared__ float tile[64][65];
    const int tid = threadIdx.x;
    const int tblk = blockIdx.x, n = blockIdx.y, b = blockIdx.z;
    #pragma unroll
    for (int it = 0; it < 4; ++it){
        int fi = it*256 + tid;            // 0..1023 float4 chunks
        int r = fi >> 4, c4 = fi & 15;
        float4 v = *(const float4*)(KVf + ((size_t)(b*TT + tblk*64 + r))*512 + 256 + n*64 + c4*4);
        tile[r][c4*4+0] = v.x; tile[r][c4*4+1] = v.y;
        tile[r][c4*4+2] = v.z; tile[r][c4*4+3] = v.w;
    }
    __syncthreads();
    const int d = tid >> 2, tseg = tid & 3;
    unsigned short tmp[16];
    #pragma unroll
    for (int i = 0; i < 16; ++i) tmp[i] = f2b(tile[tseg*16 + i][d]);
    size_t off = (((size_t)(b*HKV + n))*HD + d)*TT + tblk*64 + tseg*16;
    *(uint4*)(vat + off)     = *(const uint4*)tmp;
    *(uint4*)(vat + off + 8) = *(const uint4*)(tmp + 8);
}

// ---------------- Flash attention with MFMA ---------------------------------
// Block: (qb, h, b). 4 waves x 16 q-rows = 64-row Q tile. 64-key tiles, causal.
__global__ __launch_bounds__(256) void attn_mfma(const unsigned short* __restrict__ qa,
                                                 const unsigned short* __restrict__ ka,
                                                 const unsigned short* __restrict__ vat,
                                                 unsigned short* __restrict__ ya){
    __shared__ __align__(16) unsigned short Ks[64*72];   // [key][d], stride 72
    __shared__ __align__(16) unsigned short Vts[64*72];  // [d][key], stride 72
    __shared__ __align__(16) unsigned short Ps[4][16*72];// per-wave [q][key], stride 72

    const int tid = threadIdx.x;
    const int wave = tid >> 6, lane = tid & 63;
    const int l16 = lane & 15, quad = lane >> 4;
    const int qb = blockIdx.x, h = blockIdx.y, b = blockIdx.z;
    const int n = h >> 2;
    const int t0 = qb * 64;
    const int qrow0 = t0 + wave * 16;

    // Q fragments (A operand): rows qrow0 + l16, k = d = quad*8+j (+32)
    const unsigned short* qptr = qa + (((size_t)(b*HH + h))*TT + qrow0 + l16)*HD + quad*8;
    bf16x8 qf0 = *(const bf16x8*)qptr;
    bf16x8 qf1 = *(const bf16x8*)(qptr + 32);

    const unsigned short* kbase = ka  + ((size_t)(b*HKV + n))*TT*HD;
    const unsigned short* vbase = vat + ((size_t)(b*HKV + n))*HD*TT;

    float m_r[4] = {-1e30f,-1e30f,-1e30f,-1e30f};
    float l_r[4] = {0.f,0.f,0.f,0.f};
    f32x4 o[4] = {};

    for (int kt = 0; kt <= qb; ++kt){
        const int k0 = kt*64;
        __syncthreads();
        // stage K [key][d] and Vt [d][key]; 64x64 bf16 each = 512 uint4 chunks
        #pragma unroll
        for (int it = 0; it < 2; ++it){
            int idx = it*256 + tid;       // 0..511
            int row = idx >> 3, c = idx & 7;
            ((uint4*)Ks)[row*9 + c]  = *(const uint4*)(kbase + (size_t)(k0+row)*HD + c*8);
            ((uint4*)Vts)[row*9 + c] = *(const uint4*)(vbase + (size_t)row*TT + k0 + c*8);
        }
        __syncthreads();

        if (k0 <= qrow0 + 15){
            // S = Q K^T
            f32x4 sacc[4];
            #pragma unroll
            for (int j = 0; j < 4; ++j){
                const unsigned short* kp = Ks + (j*16 + l16)*72 + quad*8;
                bf16x8 kf0 = *(const bf16x8*)kp;
                bf16x8 kf1 = *(const bf16x8*)(kp + 32);
                f32x4 z = {};
                z = __builtin_amdgcn_mfma_f32_16x16x32_bf16(qf0, kf0, z, 0,0,0);
                sacc[j] = __builtin_amdgcn_mfma_f32_16x16x32_bf16(qf1, kf1, z, 0,0,0);
            }
            // softcap + mask + online softmax (per row r; row lives in 16 lanes of quad)
            #pragma unroll
            for (int r = 0; r < 4; ++r){
                const int qi = qrow0 + quad*4 + r;
                float mx = -1e30f;
                #pragma unroll
                for (int j = 0; j < 4; ++j){
                    float s = sacc[j][r] * 0.125f;               // * 1/sqrt(64)
                    // 50*tanh(s/50) = 50 - 100/(exp(2s/50)+1)
                    float e = exp2f(s * (0.04f * LOG2E));
                    s = 50.f - 100.f/(e + 1.f);
                    if (k0 + j*16 + l16 > qi) s = -1e30f;
                    sacc[j][r] = s;
                    mx = fmaxf(mx, s);
                }
                #pragma unroll
                for (int off2 = 1; off2 < 16; off2 <<= 1)
                    mx = fmaxf(mx, __shfl_xor(mx, off2, 64));
                float mnew = fmaxf(m_r[r], mx);
                float alpha = exp2f((m_r[r] - mnew) * LOG2E);
                m_r[r] = mnew;
                float rs = 0.f;
                #pragma unroll
                for (int j = 0; j < 4; ++j){
                    float p = exp2f((sacc[j][r] - mnew) * LOG2E);
                    rs += p;
                    Ps[wave][(quad*4 + r)*72 + j*16 + l16] = f2b(p);
                }
                #pragma unroll
                for (int off2 = 1; off2 < 16; off2 <<= 1)
                    rs += __shfl_xor(rs, off2, 64);
                l_r[r] = l_r[r]*alpha + rs;
                #pragma unroll
                for (int jd = 0; jd < 4; ++jd) o[jd][r] *= alpha;
            }
            // O += P V   (A = P [q][key], B = Vt [d][key])
            const unsigned short* pp = &Ps[wave][l16*72 + quad*8];
            bf16x8 pf0 = *(const bf16x8*)pp;
            bf16x8 pf1 = *(const bf16x8*)(pp + 32);
            #pragma unroll
            for (int jd = 0; jd < 4; ++jd){
                const unsigned short* vp = Vts + (jd*16 + l16)*72 + quad*8;
                bf16x8 vf0 = *(const bf16x8*)vp;
                bf16x8 vf1 = *(const bf16x8*)(vp + 32);
                o[jd] = __builtin_amdgcn_mfma_f32_16x16x32_bf16(pf0, vf0, o[jd], 0,0,0);
                o[jd] = __builtin_amdgcn_mfma_f32_16x16x32_bf16(pf1, vf1, o[jd], 0,0,0);
            }
        }
    }

    // epilogue: divide by l, write y (B,T,H,HD) bf16
    #pragma unroll
    for (int r = 0; r < 4; ++r){
        float inv = 1.f / l_r[r];
        int t = qrow0 + quad*4 + r;
        #pragma unroll
        for (int jd = 0; jd < 4; ++jd)
            ya[(((size_t)(b*TT + t))*HH + h)*HD + jd*16 + l16] = f2b(o[jd][r]*inv);
    }
}

// ---------------- launch ----------------------------------------------------
extern "C" void kernel_launch(void* const* d_in, const int* in_sizes, int n_in,
                              void* d_out, int out_size, void* d_ws, size_t ws_size,
                              hipStream_t stream) {
    const float* x    = (const float*)d_in[0];
    const float* w_q  = (const float*)d_in[1];
    const float* w_kv = (const float*)d_in[2];
    const float* w_c  = (const float*)d_in[3];
    const float* qw   = (const float*)d_in[4];
    const float* kw   = (const float*)d_in[5];
    float* out = (float*)d_out;

    char* ws = (char*)d_ws;
    unsigned short* xb   = (unsigned short*)(ws);
    unsigned short* wqb  = (unsigned short*)(ws + ((size_t)16<<20));
    unsigned short* wkvb = (unsigned short*)(ws + ((size_t)18<<20));
    unsigned short* wcb  = (unsigned short*)(ws + ((size_t)19<<20));
    float*          Qf   = (float*)(ws + ((size_t)21<<20));
    float*          KVf  = (float*)(ws + ((size_t)53<<20));
    unsigned short* qa   = (unsigned short*)(ws + ((size_t)69<<20));
    unsigned short* ka   = (unsigned short*)(ws + ((size_t)85<<20));
    unsigned short* vat  = (unsigned short*)(ws + ((size_t)89<<20));
    unsigned short* ya   = (unsigned short*)(ws + ((size_t)93<<20));

    // 1) convert inputs to bf16
    cvt_f32_bf16<<<dim3((MM*CC/4)/256), 256, 0, stream>>>(x, xb, MM*CC/4);
    cvt_f32_bf16<<<dim3((CC*CC/4)/256), 256, 0, stream>>>(w_q, wqb, CC*CC/4);
    cvt_f32_bf16<<<dim3((512*CC/4)/256), 256, 0, stream>>>(w_kv, wkvb, 512*CC/4);
    cvt_f32_bf16<<<dim3((CC*CC/4)/256), 256, 0, stream>>>(w_c, wcb, CC*CC/4);

    // 2) Q = x @ w_q^T ; KV = x @ w_kv^T
    gemm_bt<<<dim3(CC/128, MM/128), 256, 0, stream>>>(xb, wqb, Qf, MM, CC, CC);
    gemm_bt<<<dim3(512/128, MM/128), 256, 0, stream>>>(xb, wkvb, KVf, MM, 512, CC);

    // 3) V transpose to (b,n,d,t) bf16
    vtrans<<<dim3(TT/64, HKV, BB), 256, 0, stream>>>(KVf, vat);

    // 4) RMSNorm + RoPE for Q,K
    norm_rope<<<dim3(MM*20/4), 256, 0, stream>>>(Qf, KVf, qw, kw, qa, ka);

    // 5) flash attention
    attn_mfma<<<dim3(TT/64, HH, BB), 256, 0, stream>>>(qa, ka, vat, ya);

    // 6) out = y @ w_c^T
    gemm_bt<<<dim3(CC/128, MM/128), 256, 0, stream>>>(ya, wcb, out, MM, CC, CC);
}

// Round 3
// 325.921 us; speedup vs baseline: 5.7527x; 1.2608x over previous
//
#include <hip/hip_runtime.h>
#include <math.h>

// Problem constants
#define BB 8
#define TT 1024
#define CC 1024
#define HH 16
#define HKV 4
#define HD 64
#define GG 4
#define MM (BB*TT)   // 8192
#define LOG2E 1.4426950408889634f

typedef __attribute__((ext_vector_type(8))) short bf16x8;
typedef __attribute__((ext_vector_type(4))) float f32x4;

__device__ __forceinline__ float b2f(unsigned short x){
    union{unsigned int i; float f;} u; u.i = ((unsigned int)x)<<16; return u.f;
}
__device__ __forceinline__ unsigned short f2b(float f){
    union{float f; unsigned int i;} u; u.f = f;
    unsigned int r = u.i + 0x7fffu + ((u.i>>16)&1u);
    return (unsigned short)(r>>16);
}

// async 16B global -> LDS (gfx950 global_load_lds_dwordx4)
#define GLD16(gp, lp) __builtin_amdgcn_global_load_lds( \
    (__attribute__((address_space(1))) void*)(gp), \
    (__attribute__((address_space(3))) void*)(lp), 16, 0, 0)

// ---------------- fp32 -> bf16 conversion (vectorized) ----------------------
__global__ __launch_bounds__(256) void cvt_f32_bf16(const float* __restrict__ in,
                                                    unsigned short* __restrict__ out,
                                                    int n4){
    int i = blockIdx.x*256 + threadIdx.x;
    if (i < n4){
        float4 f = ((const float4*)in)[i];
        ushort4 o;
        o.x = f2b(f.x); o.y = f2b(f.y); o.z = f2b(f.z); o.w = f2b(f.w);
        ((ushort4*)out)[i] = o;
    }
}

// ---------------- bf16 MFMA GEMM: C(MxN fp32) = A(MxK) * Bt(NxK)^T ----------
// m97 structure: 128x128 tile, BK=32, global_load_lds width=16.
__global__ __launch_bounds__(256) void gemm_bt(const unsigned short* __restrict__ A,
                                               const unsigned short* __restrict__ Bt,
                                               float* __restrict__ Cc,
                                               int M, int N, int K){
    __shared__ __align__(16) unsigned short As[128*32];
    __shared__ __align__(16) unsigned short Bs[128*32];
    const int tid  = threadIdx.x;
    const int wid  = tid >> 6;
    const int lane = tid & 63;
    const int wm   = wid >> 1;
    const int wn   = wid & 1;
    const int l16  = lane & 15;
    const int quad = lane >> 4;
    const int bm = blockIdx.y * 128;
    const int bn = blockIdx.x * 128;

    // staging addresses: idx = it*256+tid; row = idx>>2, c = idx&3
    const int r0 = tid >> 2, c0 = tid & 3;               // idx  = tid
    const int r1 = (256+tid) >> 2, c1 = tid & 3;         // idx2 = 256+tid
    const unsigned short* a0 = A  + (size_t)(bm+r0)*K + c0*8;
    const unsigned short* a1 = A  + (size_t)(bm+r1)*K + c1*8;
    const unsigned short* b0 = Bt + (size_t)(bn+r0)*K + c0*8;
    const unsigned short* b1 = Bt + (size_t)(bn+r1)*K + c1*8;
    char* lAs0 = (char*)As + (size_t)tid*16;
    char* lAs1 = (char*)As + (size_t)(256+tid)*16;
    char* lBs0 = (char*)Bs + (size_t)tid*16;
    char* lBs1 = (char*)Bs + (size_t)(256+tid)*16;

    f32x4 acc[4][4] = {};

    for (int k0 = 0; k0 < K; k0 += 32){
        __syncthreads();
        GLD16(a0 + k0, lAs0);
        GLD16(a1 + k0, lAs1);
        GLD16(b0 + k0, lBs0);
        GLD16(b1 + k0, lBs1);
        __syncthreads();

        bf16x8 af[4], bfr[4];
        #pragma unroll
        for (int i = 0; i < 4; ++i)
            af[i] = *(const bf16x8*)(As + (wm*64 + i*16 + l16)*32 + quad*8);
        #pragma unroll
        for (int j = 0; j < 4; ++j)
            bfr[j] = *(const bf16x8*)(Bs + (wn*64 + j*16 + l16)*32 + quad*8);

        #pragma unroll
        for (int i = 0; i < 4; ++i)
            #pragma unroll
            for (int j = 0; j < 4; ++j)
                acc[i][j] = __builtin_amdgcn_mfma_f32_16x16x32_bf16(af[i], bfr[j], acc[i][j], 0, 0, 0);
    }

    #pragma unroll
    for (int i = 0; i < 4; ++i){
        int row0 = wm*64 + i*16 + quad*4;
        #pragma unroll
        for (int j = 0; j < 4; ++j){
            int col = bn + wn*64 + j*16 + l16;
            #pragma unroll
            for (int r = 0; r < 4; ++r){
                Cc[(size_t)(bm + row0 + r)*N + col] = acc[i][j][r];
            }
        }
    }
}

// ---------------- RMSNorm + RoPE + relayout (Q and K only) ------------------
__global__ __launch_bounds__(256) void norm_rope(const float* __restrict__ Qf,
                                                 const float* __restrict__ KVf,
                                                 const float* __restrict__ qw,
                                                 const float* __restrict__ kw,
                                                 unsigned short* __restrict__ qa,
                                                 unsigned short* __restrict__ ka){
    int wid  = blockIdx.x*4 + (threadIdx.x >> 6);
    int lane = threadIdx.x & 63;
    int row  = wid / 20;
    int u    = wid - row*20;
    int b = row >> 10;
    int t = row & 1023;

    float val;
    const float* w;
    if (u < 16){ val = Qf[(size_t)row*CC + u*64 + lane];        w = qw; }
    else       { val = KVf[(size_t)row*512 + (u-16)*64 + lane]; w = kw; }

    float ss = val*val;
    #pragma unroll
    for (int off = 32; off > 0; off >>= 1) ss += __shfl_xor(ss, off, 64);
    float normed = val * rsqrtf(ss*(1.0f/64.0f) + 1e-6f) * w[lane];

    int i = lane & 31;
    float freq = (float)t * exp2f(-(float)i * (13.287712379549449f/32.0f));
    float s, c;
    sincosf(freq, &s, &c);
    float other = __shfl_xor(normed, 32, 64);
    float outv = (lane < 32) ? (normed*c + other*s) : (-other*s + normed*c);

    if (u < 16){
        qa[(((size_t)(b*HH + u))*TT + t)*HD + lane] = f2b(outv);
    } else {
        ka[(((size_t)(b*HKV + (u-16)))*TT + t)*HD + lane] = f2b(outv);
    }
}

// ---------------- V transpose: KVf fp32 (b,t,[256+n*64+d]) -> vat bf16 (b,n,d,t)
__global__ __launch_bounds__(256) void vtrans(const float* __restrict__ KVf,
                                              unsigned short* __restrict__ vat){
    __shared__ float tile[64][65];
    const int tid = threadIdx.x;
    const int tblk = blockIdx.x, n = blockIdx.y, b = blockIdx.z;
    #pragma unroll
    for (int it = 0; it < 4; ++it){
        int fi = it*256 + tid;
        int r = fi >> 4, c4 = fi & 15;
        float4 v = *(const float4*)(KVf + ((size_t)(b*TT + tblk*64 + r))*512 + 256 + n*64 + c4*4);
        tile[r][c4*4+0] = v.x; tile[r][c4*4+1] = v.y;
        tile[r][c4*4+2] = v.z; tile[r][c4*4+3] = v.w;
    }
    __syncthreads();
    const int d = tid >> 2, tseg = tid & 3;
    unsigned short tmp[16];
    #pragma unroll
    for (int i = 0; i < 16; ++i) tmp[i] = f2b(tile[tseg*16 + i][d]);
    size_t off = (((size_t)(b*HKV + n))*HD + d)*TT + tblk*64 + tseg*16;
    *(uint4*)(vat + off)     = *(const uint4*)tmp;
    *(uint4*)(vat + off + 8) = *(const uint4*)(tmp + 8);
}

// ---------------- Flash attention, S^T form, fixed-cap softmax --------------
// Block: (qb, h, b). 4 waves x 16 q-rows. S^T = K·Q^T so each lane's scores
// all belong to q = lane&15. Softcap bounds scores to (-50,50] and the causal
// diagonal guarantees row-max cap >= 0, so a FIXED max of 50 replaces online
// softmax: p = exp(cap-50) in [e^-100, 1], row max >= e^-50 (bf16-normal).
__global__ __launch_bounds__(256) void attn_mfma(const unsigned short* __restrict__ qa,
                                                 const unsigned short* __restrict__ ka,
                                                 const unsigned short* __restrict__ vat,
                                                 unsigned short* __restrict__ ya){
    __shared__ __align__(16) unsigned short Ks[64*72];   // [key][d], stride 72
    __shared__ __align__(16) unsigned short Vts[64*72];  // [d][key], stride 72
    __shared__ __align__(16) unsigned short Ps[4][16*72];// per-wave [q][key]

    const int tid = threadIdx.x;
    const int wave = tid >> 6, lane = tid & 63;
    const int l16 = lane & 15, quad = lane >> 4;
    const int qb = (gridDim.x - 1) - blockIdx.x;   // heavy blocks first
    const int h = blockIdx.y, b = blockIdx.z;
    const int n = h >> 2;
    const int qrow0 = qb*64 + wave*16;

    // Q fragment (used as B operand): [n=q=l16][k=d=quad*8+j]
    const unsigned short* qptr = qa + (((size_t)(b*HH + h))*TT + qrow0 + l16)*HD + quad*8;
    bf16x8 qf0 = *(const bf16x8*)qptr;
    bf16x8 qf1 = *(const bf16x8*)(qptr + 32);

    const unsigned short* kbase = ka  + ((size_t)(b*HKV + n))*TT*HD;
    const unsigned short* vbase = vat + ((size_t)(b*HKV + n))*HD*TT;

    float lsum = 0.f;
    f32x4 o[4] = {};

    const float C1 = 0.125f * 0.04f * LOG2E;   // raw -> exponent of e^{2s/50}
    const float C2 = -100.0f * LOG2E;          // p = exp2(C2 * w)

    for (int kt = 0; kt <= qb; ++kt){
        const int k0 = kt*64;
        __syncthreads();
        #pragma unroll
        for (int it = 0; it < 2; ++it){
            int idx = it*256 + tid;
            int row = idx >> 3, c = idx & 7;
            ((uint4*)Ks)[row*9 + c]  = *(const uint4*)(kbase + (size_t)(k0+row)*HD + c*8);
            ((uint4*)Vts)[row*9 + c] = *(const uint4*)(vbase + (size_t)row*TT + k0 + c*8);
        }
        __syncthreads();

        if (k0 <= qrow0 + 15){
            // S^T = K Q^T : D[m=key][n=q]; key = j*16+quad*4+r, q = l16
            f32x4 sacc[4];
            #pragma unroll
            for (int j = 0; j < 4; ++j){
                const unsigned short* kp = Ks + (j*16 + l16)*72 + quad*8;
                bf16x8 kf0 = *(const bf16x8*)kp;
                bf16x8 kf1 = *(const bf16x8*)(kp + 32);
                f32x4 z = {};
                z = __builtin_amdgcn_mfma_f32_16x16x32_bf16(kf0, qf0, z, 0,0,0);
                sacc[j] = __builtin_amdgcn_mfma_f32_16x16x32_bf16(kf1, qf1, z, 0,0,0);
            }
            const int qrow = qrow0 + l16;
            const bool full = (k0 + 63 <= qrow0);   // wave-uniform
            #pragma unroll
            for (int j = 0; j < 4; ++j){
                ushort4 pk;
                if (full){
                    #pragma unroll
                    for (int r = 0; r < 4; ++r){
                        float e = exp2f(sacc[j][r]*C1);
                        float w = __builtin_amdgcn_rcpf(e + 1.f);
                        float p = exp2f(C2*w);
                        lsum += p;
                        ((unsigned short*)&pk)[r] = f2b(p);
                    }
                } else {
                    #pragma unroll
                    for (int r = 0; r < 4; ++r){
                        float e = exp2f(sacc[j][r]*C1);
                        float w = __builtin_amdgcn_rcpf(e + 1.f);
                        float p = exp2f(C2*w);
                        if (k0 + j*16 + quad*4 + r > qrow) p = 0.f;
                        lsum += p;
                        ((unsigned short*)&pk)[r] = f2b(p);
                    }
                }
                *(ushort4*)(&Ps[wave][l16*72 + j*16 + quad*4]) = pk;
            }
            // O += P V : A = P[q][key] from LDS, B = Vt[d][key]
            const unsigned short* pp = &Ps[wave][l16*72 + quad*8];
            bf16x8 pf0 = *(const bf16x8*)pp;
            bf16x8 pf1 = *(const bf16x8*)(pp + 32);
            #pragma unroll
            for (int jd = 0; jd < 4; ++jd){
                const unsigned short* vp = Vts + (jd*16 + l16)*72 + quad*8;
                bf16x8 vf0 = *(const bf16x8*)vp;
                bf16x8 vf1 = *(const bf16x8*)(vp + 32);
                o[jd] = __builtin_amdgcn_mfma_f32_16x16x32_bf16(pf0, vf0, o[jd], 0,0,0);
                o[jd] = __builtin_amdgcn_mfma_f32_16x16x32_bf16(pf1, vf1, o[jd], 0,0,0);
            }
        }
    }

    // final l reduction over quads (q = l16 replicated in each quad)
    lsum += __shfl_xor(lsum, 16, 64);
    lsum += __shfl_xor(lsum, 32, 64);
    float inv = __builtin_amdgcn_rcpf(lsum);

    // epilogue: O is C-layout (row=q=quad*4+r, col=d=jd*16+l16); fetch inv(q)
    #pragma unroll
    for (int r = 0; r < 4; ++r){
        float linv = __shfl(inv, (lane & 48) | (quad*4 + r), 64);
        int t = qrow0 + quad*4 + r;
        #pragma unroll
        for (int jd = 0; jd < 4; ++jd)
            ya[(((size_t)(b*TT + t))*HH + h)*HD + jd*16 + l16] = f2b(o[jd][r]*linv);
    }
}

// ---------------- launch ----------------------------------------------------
extern "C" void kernel_launch(void* const* d_in, const int* in_sizes, int n_in,
                              void* d_out, int out_size, void* d_ws, size_t ws_size,
                              hipStream_t stream) {
    const float* x    = (const float*)d_in[0];
    const float* w_q  = (const float*)d_in[1];
    const float* w_kv = (const float*)d_in[2];
    const float* w_c  = (const float*)d_in[3];
    const float* qw   = (const float*)d_in[4];
    const float* kw   = (const float*)d_in[5];
    float* out = (float*)d_out;

    char* ws = (char*)d_ws;
    unsigned short* xb   = (unsigned short*)(ws);
    unsigned short* wqb  = (unsigned short*)(ws + ((size_t)16<<20));
    unsigned short* wkvb = (unsigned short*)(ws + ((size_t)18<<20));
    unsigned short* wcb  = (unsigned short*)(ws + ((size_t)19<<20));
    float*          Qf   = (float*)(ws + ((size_t)21<<20));
    float*          KVf  = (float*)(ws + ((size_t)53<<20));
    unsigned short* qa   = (unsigned short*)(ws + ((size_t)69<<20));
    unsigned short* ka   = (unsigned short*)(ws + ((size_t)85<<20));
    unsigned short* vat  = (unsigned short*)(ws + ((size_t)89<<20));
    unsigned short* ya   = (unsigned short*)(ws + ((size_t)93<<20));

    // 1) convert inputs to bf16
    cvt_f32_bf16<<<dim3((MM*CC/4)/256), 256, 0, stream>>>(x, xb, MM*CC/4);
    cvt_f32_bf16<<<dim3((CC*CC/4)/256), 256, 0, stream>>>(w_q, wqb, CC*CC/4);
    cvt_f32_bf16<<<dim3((512*CC/4)/256), 256, 0, stream>>>(w_kv, wkvb, 512*CC/4);
    cvt_f32_bf16<<<dim3((CC*CC/4)/256), 256, 0, stream>>>(w_c, wcb, CC*CC/4);

    // 2) Q = x @ w_q^T ; KV = x @ w_kv^T
    gemm_bt<<<dim3(CC/128, MM/128), 256, 0, stream>>>(xb, wqb, Qf, MM, CC, CC);
    gemm_bt<<<dim3(512/128, MM/128), 256, 0, stream>>>(xb, wkvb, KVf, MM, 512, CC);

    // 3) V transpose to (b,n,d,t) bf16
    vtrans<<<dim3(TT/64, HKV, BB), 256, 0, stream>>>(KVf, vat);

    // 4) RMSNorm + RoPE for Q,K
    norm_rope<<<dim3(MM*20/4), 256, 0, stream>>>(Qf, KVf, qw, kw, qa, ka);

    // 5) flash attention
    attn_mfma<<<dim3(TT/64, HH, BB), 256, 0, stream>>>(qa, ka, vat, ya);

    // 6) out = y @ w_c^T
    gemm_bt<<<dim3(CC/128, MM/128), 256, 0, stream>>>(ya, wcb, out, MM, CC, CC);
}